// Round 13
// baseline (167.893 us; speedup 1.0000x reference)
//
#include <hip/hip_runtime.h>

#define B_    8
#define V_    50000
#define KNB   9
#define CIN_  64
#define COUT_ 128
#define VOUT_ 12500
#define NNZ_  37500
#define KTOT  576      // KNB*CIN_
#define M_    400000   // B_*V_
#define NWG   3125     // M_/128

typedef short bf16x8 __attribute__((ext_vector_type(8)));
typedef float f32x4  __attribute__((ext_vector_type(4)));

#define AS1 __attribute__((address_space(1)))
#define AS3 __attribute__((address_space(3)))

__device__ __forceinline__ unsigned short f2bf(float f) {
  unsigned u = __float_as_uint(f);
  u += 0x7fffu + ((u >> 16) & 1u);          // RNE
  return (unsigned short)(u >> 16);
}
__device__ __forceinline__ unsigned pack2(float lo, float hi) {
  return (unsigned)f2bf(lo) | ((unsigned)f2bf(hi) << 16);
}
__device__ __forceinline__ float bf2f(unsigned short u) {
  return __uint_as_float((unsigned)u << 16);
}

__device__ __forceinline__ void gld_lds16(const void* g, void* l) {
  __builtin_amdgcn_global_load_lds((const AS1 unsigned*)g, (AS3 unsigned*)l, 16, 0, 0);
}

// Fused prep: [0,36) W->frag-major bf16; [36,183) pool bucket-fill; [183,2231)
// convert x fp32->bf16 (grid-stride).
#define PREP_WBLK 36
#define PREP_FBLK 147
#define PREP_XBLK 2048
__global__ __launch_bounds__(256) void prep(const float* __restrict__ w,
                                            unsigned short* __restrict__ wfr,
                                            const float* __restrict__ x,
                                            unsigned short* __restrict__ xbf,
                                            const int* __restrict__ dr,
                                            const int* __restrict__ dc,
                                            const float* __restrict__ dd,
                                            int* __restrict__ cursor,
                                            int2* __restrict__ elist) {
  const int bid = blockIdx.x;
  if (bid < PREP_WBLK) {
    // W -> MFMA-fragment-major: chunk i holds, for lane=i&63, n=(i>>6)&3,
    // wc=(i>>8)&1, ks=(i>>9)&1, t=i>>10:
    //   W[col=wc*64+n*16+(lane&15)][k=t*64+ks*32+(lane>>4)*8 .. +8]
    int i = bid * 256 + threadIdx.x;        // 0..9215
    int lane = i & 63, n = (i >> 6) & 3, wc = (i >> 8) & 1, ks = (i >> 9) & 1, t = i >> 10;
    int col = wc * 64 + n * 16 + (lane & 15);
    int k0 = t * 64 + ks * 32 + (lane >> 4) * 8;
    const float* src = w + (size_t)col * KTOT + k0;
    float4 f0 = reinterpret_cast<const float4*>(src)[0];
    float4 f1 = reinterpret_cast<const float4*>(src)[1];
    uint4 o;
    o.x = pack2(f0.x, f0.y);
    o.y = pack2(f0.z, f0.w);
    o.z = pack2(f1.x, f1.y);
    o.w = pack2(f1.z, f1.w);
    reinterpret_cast<uint4*>(wfr)[i] = o;
  } else if (bid < PREP_WBLK + PREP_FBLK) {
    int e = (bid - PREP_WBLK) * 256 + threadIdx.x;
    if (e < NNZ_) {
      int r = dr[e];
      int slot = atomicAdd(&cursor[r], 1);
      if (slot < 32) elist[r * 32 + slot] = make_int2(dc[e], __float_as_int(dd[e]));
    }
  } else {
    const int nq = B_ * V_ * CIN_ / 4;      // 6.4M float4 quads
    for (int q = (bid - PREP_WBLK - PREP_FBLK) * 256 + threadIdx.x; q < nq;
         q += PREP_XBLK * 256) {
      float4 f = reinterpret_cast<const float4*>(x)[q];
      ushort4 o;
      o.x = f2bf(f.x); o.y = f2bf(f.y); o.z = f2bf(f.z); o.w = f2bf(f.w);
      reinterpret_cast<ushort4*>(xbf)[q] = o;
    }
  }
}

// h = elu(gather(x) @ W^T + bias). 128x128 tile, 4 waves, BK=64.
// R13: single-bank B issued FIRST each iter, then A(t+2) gld_lds. With in-order
// vmcnt retirement, the compiler's own dribbling waits for the bk registers land
// at vmcnt(4): they retire B(t) and the PREVIOUS iter's A-stage but never block
// on A(t+2) -> A-pipeline (2-deep) intact with NO hand-written vmcnt (one
// prologue vmcnt(4) only). Raw s_barrier per iter (no __syncthreads drain).
// Single-bank B cuts 32 VGPRs vs R12 (84+64agpr=148 -> 3 waves/SIMD was the
// real residency limiter; target <=128 total for 4/SIMD, LDS gives 3 blocks).
// Entry-of-iter-t A(t) guarantee: iter t-1's bk-waits (vmcnt(4)) retired A(t)
// (issued before B(t-1) in iter t-2); entry barrier publishes across waves.
struct GemmSM { char A[3][16384]; unsigned short spc[1152]; };  // 51,456 B

__global__ __launch_bounds__(256, 3) void spiral_gemm(
    const unsigned short* __restrict__ xbf, const unsigned short* __restrict__ wfr,
    const float* __restrict__ bias, const int* __restrict__ sp,
    unsigned short* __restrict__ hbf)
{
  __shared__ GemmSM smv;
  GemmSM* sm = &smv;

  // ---- bijective XCD swizzle (nwg=3125: q=390, r=5)
  const int q_ = NWG / 8, r_ = NWG % 8;
  const int xcd = blockIdx.x & 7, pos = blockIdx.x >> 3;
  const int nbid = (xcd < r_) ? xcd * (q_ + 1) + pos
                              : r_ * (q_ + 1) + (xcd - r_) * q_ + pos;

  const int tid  = threadIdx.x;
  const int m0   = nbid * 128;
  const int wave = tid >> 6;
  const int lane = tid & 63;

  // ---- cache all 1152 spiral indices (ushort) for this tile in LDS
  for (int i = tid; i < 128 * KNB; i += 256) {
    int row = i / KNB, j = i - row * KNB;
    int m = m0 + row;
    int b = m / V_;
    int v = m - b * V_;
    sm->spc[i] = (unsigned short)sp[v * KNB + j];
  }

  // ---- staging geometry: 4 rounds x 32 rows, 8 lanes x 16B chunks per 128B row
  const int rrow  = tid >> 3;                       // 0..31
  const int chunkoff = (((tid & 7) ^ (rrow & 7)) << 4); // inverse-swizzled source chunk
  unsigned boff[4];
  int sbase[4], ldso[4];
  #pragma unroll
  for (int r = 0; r < 4; ++r) {
    int row = r * 32 + rrow;
    int m = m0 + row;
    int b = m / V_;
    boff[r]  = (unsigned)b * (V_ * CIN_ * 2);       // byte offset of batch slice
    sbase[r] = row * KNB;
    ldso[r]  = (r * 32 + wave * 8) * 128;
  }

  // ---- compute geometry
  const int wr = wave >> 1, wc = wave & 1;
  const int lr = lane & 15, lg = lane >> 4;
  const bf16x8* wbase = (const bf16x8*)wfr + wc * 256 + lane;   // +((t*2+ks)*512 + n*64)

  f32x4 acc[4][4];
  #pragma unroll
  for (int i = 0; i < 4; ++i)
    #pragma unroll
    for (int j = 0; j < 4; ++j)
      acc[i][j] = (f32x4){0.f, 0.f, 0.f, 0.f};

  auto stageA = [&](int bi, int t) {
    char* Ab = sm->A[bi];
    #pragma unroll
    for (int r = 0; r < 4; ++r) {
      unsigned idx = sm->spc[sbase[r] + t];         // LDS read (lgkm domain)
      unsigned off = boff[r] + idx * 128u + (unsigned)chunkoff;
      gld_lds16((const char*)xbf + off, Ab + ldso[r]);
    }
  };

  // ---- prologue: publish spc; stage A(0), A(1); retire A(0), keep A(1) in flight
  __syncthreads();
  stageA(0, 0);
  stageA(1, 1);
  asm volatile("s_waitcnt vmcnt(4)" ::: "memory");   // A(0) done; A(1) in flight
  __builtin_amdgcn_sched_barrier(0);

#define GITER(T)                                                                \
  do {                                                                          \
    __builtin_amdgcn_s_barrier();          /* publish A(T) across waves */      \
    __builtin_amdgcn_sched_barrier(0);                                          \
    bf16x8 bk[2][4];                       /* B(T): issued FIRST (8 loads) */   \
    _Pragma("unroll")                                                           \
    for (int ks = 0; ks < 2; ++ks)                                              \
      _Pragma("unroll")                                                         \
      for (int n = 0; n < 4; ++n)                                               \
        bk[ks][n] = wbase[((T) * 2 + ks) * 512 + n * 64];                       \
    __builtin_amdgcn_sched_barrier(0);                                          \
    if ((T) + 2 < KNB) stageA(((T) + 2) % 3, (T) + 2);  /* A(T+2) AFTER B */    \
    __builtin_amdgcn_sched_barrier(0);                                          \
    {                                                                           \
      const char* Ab = sm->A[(T) % 3];                                          \
      _Pragma("unroll")                                                         \
      for (int ks = 0; ks < 2; ++ks) {                                          \
        const int kb = ks * 64 + lg * 16;                                       \
        bf16x8 af[4];                                                           \
        _Pragma("unroll")                                                       \
        for (int m = 0; m < 4; ++m) {                                           \
          int row = wr * 64 + m * 16 + lr;                                      \
          af[m] = *reinterpret_cast<const bf16x8*>(                             \
              Ab + row * 128 + (kb ^ ((row & 7) << 4)));                        \
        }                                                                       \
        __builtin_amdgcn_s_setprio(1);                                          \
        _Pragma("unroll")                                                       \
        for (int m = 0; m < 4; ++m)                                             \
          _Pragma("unroll")                                                     \
          for (int n = 0; n < 4; ++n)                                           \
            acc[m][n] = __builtin_amdgcn_mfma_f32_16x16x32_bf16(                \
                af[m], bk[ks][n], acc[m][n], 0, 0, 0);                          \
        __builtin_amdgcn_s_setprio(0);                                          \
      }                                                                         \
    }                                                                           \
    __builtin_amdgcn_sched_barrier(0);                                          \
  } while (0)

  GITER(0);
  GITER(1);
  GITER(2);
  GITER(3);
  GITER(4);
  GITER(5);
  GITER(6);
  GITER(7);
  GITER(8);
#undef GITER

  // ---- epilogue: bias + ELU -> bf16 into swizzled hs over A[0..1] (32KB),
  //      then coalesced 16B global stores.
  __syncthreads();
  char* hsb = (char*)sm;
  #pragma unroll
  for (int n = 0; n < 4; ++n) {
    const int c = wc * 64 + n * 16 + lr;
    const float bv = bias[c];
    #pragma unroll
    for (int m = 0; m < 4; ++m) {
      const int row0 = wr * 64 + m * 16 + lg * 4;
      #pragma unroll
      for (int j = 0; j < 4; ++j) {
        const int row = row0 + j;
        float vv = acc[m][n][j] + bv;
        vv = vv > 0.f ? vv : (__expf(vv) - 1.f);
        *reinterpret_cast<unsigned short*>(
            hsb + row * 256 + ((c * 2) ^ ((row & 7) << 4))) = f2bf(vv);
      }
    }
  }
  __syncthreads();
  const int r2 = tid >> 1, hf = tid & 1;
  uint4* drow = reinterpret_cast<uint4*>(hbf + (size_t)(m0 + r2) * COUT_ + hf * 64);
  #pragma unroll
  for (int u = 0; u < 8; ++u) {
    int cb = hf * 128 + u * 16;
    drow[u] = *reinterpret_cast<const uint4*>(hsb + r2 * 256 + (cb ^ ((r2 & 7) << 4)));
  }
}

// One block per output row; 8 b-groups x 32 lanes; bucketed entries (cap 32).
__global__ __launch_bounds__(256) void pool_rows(const unsigned short* __restrict__ hbf,
                                                 const int* __restrict__ cursor,
                                                 const int2* __restrict__ elist,
                                                 float* __restrict__ out) {
  const int row = blockIdx.x;
  const int bg = threadIdx.x >> 5;     // batch 0..7
  const int lc = threadIdx.x & 31;     // c-quad 0..31
  int cnt = cursor[row];
  cnt = cnt < 32 ? cnt : 32;
  const unsigned short* hb = hbf + (size_t)bg * (V_ * COUT_) + lc * 4;
  float4 acc = {0.f, 0.f, 0.f, 0.f};
  for (int e = 0; e < cnt; ++e) {
    int2 en = elist[row * 32 + e];
    float d = __int_as_float(en.y);
    ushort4 v = *reinterpret_cast<const ushort4*>(hb + (size_t)en.x * COUT_);
    acc.x += d * bf2f(v.x);
    acc.y += d * bf2f(v.y);
    acc.z += d * bf2f(v.z);
    acc.w += d * bf2f(v.w);
  }
  *reinterpret_cast<float4*>(out + ((size_t)bg * VOUT_ + row) * COUT_ + lc * 4) = acc;
}

extern "C" void kernel_launch(void* const* d_in, const int* in_sizes, int n_in,
                              void* d_out, int out_size, void* d_ws, size_t ws_size,
                              hipStream_t stream) {
  const float* x    = (const float*)d_in[0];
  const float* w    = (const float*)d_in[1];
  const float* bias = (const float*)d_in[2];
  const int*   sp   = (const int*)d_in[3];
  const int*   dr   = (const int*)d_in[4];
  const int*   dc   = (const int*)d_in[5];
  const float* dd   = (const float*)d_in[6];
  float* out = (float*)d_out;

  char* ws = (char*)d_ws;
  unsigned short* wfr = (unsigned short*)ws;                       // 147,456 B (frag-major)
  unsigned short* xbf = (unsigned short*)(ws + 147456);            // 51,200,000 B
  unsigned short* hbf = (unsigned short*)(ws + 51347456);          // 102,400,000 B
  int*  cursor  = (int*) (ws + 153747456);                         // 50,000 B
  int2* elist   = (int2*)(ws + 153797456);                         // 3,200,000 B

  hipMemsetAsync(cursor, 0, VOUT_ * sizeof(int), stream);
  prep<<<PREP_WBLK + PREP_FBLK + PREP_XBLK, 256, 0, stream>>>(
      w, wfr, x, xbf, dr, dc, dd, cursor, elist);
  spiral_gemm<<<NWG, 256, 0, stream>>>(xbf, wfr, bias, sp, hbf);
  pool_rows<<<VOUT_, 256, 0, stream>>>(hbf, cursor, elist, out);
}

// Round 15
// 123.879 us; speedup vs baseline: 1.3553x; 1.3553x over previous
//
#include <hip/hip_runtime.h>

#define B_    8
#define V_    50000
#define KNB   9
#define CIN_  64
#define COUT_ 128
#define VOUT_ 12500
#define NNZ_  37500
#define KTOT  576      // KNB*CIN_
#define NWG   3125     // worst-case grid (U=V): 8*V/128

typedef short bf16x8 __attribute__((ext_vector_type(8)));
typedef float f32x4  __attribute__((ext_vector_type(4)));

#define AS1 __attribute__((address_space(1)))
#define AS3 __attribute__((address_space(3)))

__device__ __forceinline__ unsigned short f2bf(float f) {
  unsigned u = __float_as_uint(f);
  u += 0x7fffu + ((u >> 16) & 1u);          // RNE
  return (unsigned short)(u >> 16);
}
__device__ __forceinline__ unsigned pack2(float lo, float hi) {
  return (unsigned)f2bf(lo) | ((unsigned)f2bf(hi) << 16);
}
__device__ __forceinline__ float bf2f(unsigned short u) {
  return __uint_as_float((unsigned)u << 16);
}

__device__ __forceinline__ void gld_lds16(const void* g, void* l) {
  __builtin_amdgcn_global_load_lds((const AS1 unsigned*)g, (AS3 unsigned*)l, 16, 0, 0);
}

// Fused prep: [0,36) W->frag-major bf16; [36,183) pool bucket-fill + USED-COLUMN
// COMPACTION (only ~53% of h rows are ever pooled: dt_col covers ~26.4k of 50k
// cols; the used set is batch-independent); [183,2231) convert x fp32->bf16.
#define PREP_WBLK 36
#define PREP_FBLK 147
#define PREP_XBLK 2048
__global__ __launch_bounds__(256) void prep(const float* __restrict__ w,
                                            unsigned short* __restrict__ wfr,
                                            const float* __restrict__ x,
                                            unsigned short* __restrict__ xbf,
                                            const int* __restrict__ dr,
                                            const int* __restrict__ dc,
                                            const float* __restrict__ dd,
                                            int* __restrict__ cursor,
                                            int* __restrict__ used,
                                            int* __restrict__ Ucnt,
                                            int2* __restrict__ elist,
                                            int* __restrict__ rmap,
                                            int* __restrict__ cidx) {
  const int bid = blockIdx.x;
  if (bid < PREP_WBLK) {
    // W -> MFMA-fragment-major: chunk i holds, for lane=i&63, n=(i>>6)&3,
    // wc=(i>>8)&1, ks=(i>>9)&1, t=i>>10:
    //   W[col=wc*64+n*16+(lane&15)][k=t*64+ks*32+(lane>>4)*8 .. +8]
    int i = bid * 256 + threadIdx.x;        // 0..9215
    int lane = i & 63, n = (i >> 6) & 3, wc = (i >> 8) & 1, ks = (i >> 9) & 1, t = i >> 10;
    int col = wc * 64 + n * 16 + (lane & 15);
    int k0 = t * 64 + ks * 32 + (lane >> 4) * 8;
    const float* src = w + (size_t)col * KTOT + k0;
    float4 f0 = reinterpret_cast<const float4*>(src)[0];
    float4 f1 = reinterpret_cast<const float4*>(src)[1];
    uint4 o;
    o.x = pack2(f0.x, f0.y);
    o.y = pack2(f0.z, f0.w);
    o.z = pack2(f1.x, f1.y);
    o.w = pack2(f1.z, f1.w);
    reinterpret_cast<uint4*>(wfr)[i] = o;
  } else if (bid < PREP_WBLK + PREP_FBLK) {
    int e = (bid - PREP_WBLK) * 256 + threadIdx.x;
    if (e < NNZ_) {
      int r = dr[e], c = dc[e];
      int slot = atomicAdd(&cursor[r], 1);
      if (slot < 32) elist[r * 32 + slot] = make_int2(c, __float_as_int(dd[e]));
      if (atomicExch(&used[c], 1) == 0) {       // first toucher compacts this col
        int u = atomicAdd(Ucnt, 1);
        rmap[u] = c;
        cidx[c] = u;
      }
    }
  } else {
    const int nq = B_ * V_ * CIN_ / 4;      // 6.4M float4 quads
    for (int q = (bid - PREP_WBLK - PREP_FBLK) * 256 + threadIdx.x; q < nq;
         q += PREP_XBLK * 256) {
      float4 f = reinterpret_cast<const float4*>(x)[q];
      ushort4 o;
      o.x = f2bf(f.x); o.y = f2bf(f.y); o.z = f2bf(f.z); o.w = f2bf(f.w);
      reinterpret_cast<ushort4*>(xbf)[q] = o;
    }
  }
}

// h = elu(gather(x) @ W^T + bias) for COMPACTED rows m' = b*U + u, v = rmap[u].
// Loop structure = R12 verbatim (best of 6 structures, 103us): A 3-buf LDS
// 2-deep gld_lds pipeline, B double-banked registers, raw s_barrier per iter,
// hand vmcnt {4,12,8} (A(t) staged at t-2; at entry of t the 12 younger ops are
// B(t)x8+A(t+1)x4). Blocks >= nact(U) exit; XCD swizzle over nact keeps the
// active set spread across all 8 XCDs.
struct GemmSM { char A[3][16384]; unsigned short spc[1152]; };  // 51,456 B

__global__ __launch_bounds__(256, 3) void spiral_gemm(
    const unsigned short* __restrict__ xbf, const unsigned short* __restrict__ wfr,
    const float* __restrict__ bias, const int* __restrict__ sp,
    const int* __restrict__ rmap, const int* __restrict__ Ucnt,
    unsigned short* __restrict__ hbf)
{
  __shared__ GemmSM smv;
  GemmSM* sm = &smv;

  const int U    = *Ucnt;
  const int Mtot = 8 * U;
  const int nact = (Mtot + 127) >> 7;
  if ((int)blockIdx.x >= nact) return;

  // ---- bijective XCD swizzle over the ACTIVE block count
  const int q_ = nact >> 3, r_ = nact & 7;
  const int xcd = blockIdx.x & 7, pos = blockIdx.x >> 3;
  const int nbid = (xcd < r_) ? xcd * (q_ + 1) + pos
                              : r_ * (q_ + 1) + (xcd - r_) * q_ + pos;

  const int tid  = threadIdx.x;
  const int m0   = nbid * 128;
  const int wave = tid >> 6;
  const int lane = tid & 63;

  // ---- cache spiral indices for this tile's 128 compact rows (ushort)
  for (int i = tid; i < 128 * KNB; i += 256) {
    int row = i / KNB, j = i - row * KNB;
    int mp = m0 + row;
    int v = 0;
    if (mp < Mtot) { int b = mp / U; v = rmap[mp - b * U]; }
    sm->spc[i] = (unsigned short)sp[v * KNB + j];
  }

  // ---- staging geometry: 4 rounds x 32 rows, 8 lanes x 16B chunks per 128B row
  const int rrow  = tid >> 3;                       // 0..31
  const int chunkoff = (((tid & 7) ^ (rrow & 7)) << 4); // inverse-swizzled source chunk
  unsigned boff[4];
  int sbase[4], ldso[4];
  #pragma unroll
  for (int r = 0; r < 4; ++r) {
    int row = r * 32 + rrow;
    int mp = m0 + row;
    int b = (mp < Mtot) ? (mp / U) : 0;
    boff[r]  = (unsigned)b * (V_ * CIN_ * 2);       // byte offset of batch slice
    sbase[r] = row * KNB;
    ldso[r]  = (r * 32 + wave * 8) * 128;
  }

  // ---- compute geometry
  const int wr = wave >> 1, wc = wave & 1;
  const int lr = lane & 15, lg = lane >> 4;
  const bf16x8* wbase = (const bf16x8*)wfr + wc * 256 + lane;   // +((t*2+ks)*512 + n*64)

  f32x4 acc[4][4];
  #pragma unroll
  for (int i = 0; i < 4; ++i)
    #pragma unroll
    for (int j = 0; j < 4; ++j)
      acc[i][j] = (f32x4){0.f, 0.f, 0.f, 0.f};

  auto stageA = [&](int bi, int t) {
    char* Ab = sm->A[bi];
    #pragma unroll
    for (int r = 0; r < 4; ++r) {
      unsigned idx = sm->spc[sbase[r] + t];         // LDS read (lgkm domain)
      unsigned off = boff[r] + idx * 128u + (unsigned)chunkoff;
      gld_lds16((const char*)xbf + off, Ab + ldso[r]);
    }
  };

  bf16x8 b0[2][4], b1[2][4];
  auto loadB = [&](bf16x8 (&bk)[2][4], int t) {
    #pragma unroll
    for (int ks = 0; ks < 2; ++ks)
      #pragma unroll
      for (int n = 0; n < 4; ++n)
        bk[ks][n] = wbase[(t * 2 + ks) * 512 + n * 64];
  };

  // ---- prologue (spc visible to all; then B(0)x8, A(0)x4, A(1)x4)
  __syncthreads();
  loadB(b0, 0);
  stageA(0, 0);
  stageA(1, 1);

#define GITER(T, BC, BN)                                                        \
  do {                                                                          \
    asm volatile("s_waitcnt vmcnt(%0)"                                          \
                 :: "i"((T) == 0 ? 4 : ((T) <= 7 ? 12 : 8)) : "memory");        \
    __builtin_amdgcn_sched_barrier(0);                                          \
    __builtin_amdgcn_s_barrier();                                               \
    if ((T) + 1 < KNB) loadB(BN, (T) + 1);                                      \
    __builtin_amdgcn_sched_barrier(0);                                          \
    if ((T) + 2 < KNB) stageA(((T) + 2) % 3, (T) + 2);                          \
    __builtin_amdgcn_sched_barrier(0);                                          \
    {                                                                           \
      const char* Ab = sm->A[(T) % 3];                                          \
      _Pragma("unroll")                                                         \
      for (int ks = 0; ks < 2; ++ks) {                                          \
        const int kb = ks * 64 + lg * 16;                                       \
        bf16x8 af[4];                                                           \
        _Pragma("unroll")                                                       \
        for (int m = 0; m < 4; ++m) {                                           \
          int row = wr * 64 + m * 16 + lr;                                      \
          af[m] = *reinterpret_cast<const bf16x8*>(                             \
              Ab + row * 128 + (kb ^ ((row & 7) << 4)));                        \
        }                                                                       \
        __builtin_amdgcn_s_setprio(1);                                          \
        _Pragma("unroll")                                                       \
        for (int m = 0; m < 4; ++m)                                             \
          _Pragma("unroll")                                                     \
          for (int n = 0; n < 4; ++n)                                           \
            acc[m][n] = __builtin_amdgcn_mfma_f32_16x16x32_bf16(                \
                af[m], BC[ks][n], acc[m][n], 0, 0, 0);                          \
        __builtin_amdgcn_s_setprio(0);                                          \
      }                                                                         \
    }                                                                           \
    asm volatile("s_waitcnt lgkmcnt(0)" ::: "memory");                          \
    __builtin_amdgcn_sched_barrier(0);                                          \
  } while (0)

  GITER(0, b0, b1);
  GITER(1, b1, b0);
  GITER(2, b0, b1);
  GITER(3, b1, b0);
  GITER(4, b0, b1);
  GITER(5, b1, b0);
  GITER(6, b0, b1);
  GITER(7, b1, b0);
  GITER(8, b0, b1);
#undef GITER

  // ---- epilogue: bias + ELU -> bf16 into swizzled hs over A[0..1] (32KB),
  //      then coalesced 16B global stores (guarded for the partial last tile).
  __syncthreads();
  char* hsb = (char*)sm;
  #pragma unroll
  for (int n = 0; n < 4; ++n) {
    const int c = wc * 64 + n * 16 + lr;
    const float bv = bias[c];
    #pragma unroll
    for (int m = 0; m < 4; ++m) {
      const int row0 = wr * 64 + m * 16 + lg * 4;
      #pragma unroll
      for (int j = 0; j < 4; ++j) {
        const int row = row0 + j;
        float vv = acc[m][n][j] + bv;
        vv = vv > 0.f ? vv : (__expf(vv) - 1.f);
        *reinterpret_cast<unsigned short*>(
            hsb + row * 256 + ((c * 2) ^ ((row & 7) << 4))) = f2bf(vv);
      }
    }
  }
  __syncthreads();
  const int r2 = tid >> 1, hf = tid & 1;
  if (m0 + r2 < Mtot) {
    uint4* drow = reinterpret_cast<uint4*>(hbf + (size_t)(m0 + r2) * COUT_ + hf * 64);
    #pragma unroll
    for (int u = 0; u < 8; ++u) {
      int cb = hf * 128 + u * 16;
      drow[u] = *reinterpret_cast<const uint4*>(hsb + r2 * 256 + (cb ^ ((r2 & 7) << 4)));
    }
  }
}

// One block per output row; 8 b-groups x 32 lanes; bucketed entries (cap 32).
// h is COMPACT: row for col c of batch b lives at hbf[(b*U + cidx[c]) * 128].
__global__ __launch_bounds__(256) void pool_rows(const unsigned short* __restrict__ hbf,
                                                 const int* __restrict__ cursor,
                                                 const int2* __restrict__ elist,
                                                 const int* __restrict__ cidx,
                                                 const int* __restrict__ Ucnt,
                                                 float* __restrict__ out) {
  const int row = blockIdx.x;
  const int bg = threadIdx.x >> 5;     // batch 0..7
  const int lc = threadIdx.x & 31;     // c-quad 0..31
  const int U = *Ucnt;
  int cnt = cursor[row];
  cnt = cnt < 32 ? cnt : 32;
  const unsigned short* hb = hbf + (size_t)bg * U * COUT_ + lc * 4;
  float4 acc = {0.f, 0.f, 0.f, 0.f};
  for (int e = 0; e < cnt; ++e) {
    int2 en = elist[row * 32 + e];
    float d = __int_as_float(en.y);
    int u = cidx[en.x];
    ushort4 v = *reinterpret_cast<const ushort4*>(hb + (size_t)u * COUT_);
    acc.x += d * bf2f(v.x);
    acc.y += d * bf2f(v.y);
    acc.z += d * bf2f(v.z);
    acc.w += d * bf2f(v.w);
  }
  *reinterpret_cast<float4*>(out + ((size_t)bg * VOUT_ + row) * COUT_ + lc * 4) = acc;
}

extern "C" void kernel_launch(void* const* d_in, const int* in_sizes, int n_in,
                              void* d_out, int out_size, void* d_ws, size_t ws_size,
                              hipStream_t stream) {
  const float* x    = (const float*)d_in[0];
  const float* w    = (const float*)d_in[1];
  const float* bias = (const float*)d_in[2];
  const int*   sp   = (const int*)d_in[3];
  const int*   dr   = (const int*)d_in[4];
  const int*   dc   = (const int*)d_in[5];
  const float* dd   = (const float*)d_in[6];
  float* out = (float*)d_out;

  char* ws = (char*)d_ws;
  unsigned short* wfr = (unsigned short*)ws;        // 147456 B (frag-major W)
  unsigned short* xbf = (unsigned short*)(ws + 147456);     // 51200000 B
  unsigned short* hbf = (unsigned short*)(ws + 51347456);   // 102400000 B worst case
  int*  cursor  = (int*) (ws + 153747456);          // 50000 B (memset with used+Ucnt)
  int*  used    = (int*) (ws + 153797456);          // 200000 B
  int*  Ucnt    = (int*) (ws + 153997456);          // 16 B
  int2* elist   = (int2*)(ws + 153997472);          // 3200000 B
  int*  rmap    = (int*) (ws + 157197472);          // 200000 B
  int*  cidx    = (int*) (ws + 157397472);          // 200000 B

  (void)hipMemsetAsync(cursor, 0, 250016, stream);  // cursor + used + Ucnt
  prep<<<PREP_WBLK + PREP_FBLK + PREP_XBLK, 256, 0, stream>>>(
      w, wfr, x, xbf, dr, dc, dd, cursor, used, Ucnt, elist, rmap, cidx);
  spiral_gemm<<<NWG, 256, 0, stream>>>(xbf, wfr, bias, sp, rmap, Ucnt, hbf);
  pool_rows<<<VOUT_, 256, 0, stream>>>(hbf, cursor, elist, cidx, Ucnt, out);
}